// Round 2
// baseline (32926.828 us; speedup 1.0000x reference)
//
#include <hip/hip_runtime.h>

typedef __attribute__((ext_vector_type(8))) short short8;
typedef __attribute__((ext_vector_type(4))) float f32x4;

#define HD 1024
#define BD 64
#define TD 512
#define BH 65536UL  // 64*1024
#define NBLK 194

// ---------------- workspace layout ----------------
// ushort (bf16) region first, then float region. All offsets in elements.
#define M4 4194304UL
#define OFF_WHH0 0UL
#define OFF_WIH1 (1UL * M4)
#define OFF_WHH1 (2UL * M4)
#define OFF_WIH2 (3UL * M4)
#define OFF_WHH2 (4UL * M4)
#define OFF_WOUT (5UL * M4)                 // 128 x 1024 (padded rows zeroed)
#define OFF_H0   (OFF_WOUT + 131072UL)      // [2][64][1024] each
#define OFF_H1   (OFF_H0 + 131072UL)
#define OFF_H2   (OFF_H1 + 131072UL)
#define USHORT_TOTAL (OFF_H2 + 131072UL)    // 21,495,808 ushorts
#define FBYTE_BASE (USHORT_TOTAL * 2UL)     // byte offset of float region (16B aligned)
#define FOFF_C0 0UL                          // c stored [j][b] (transposed)
#define FOFF_C1 65536UL
#define FOFF_C2 131072UL
#define FOFF_B0 196608UL                     // combined biases b_ih+b_hh [4096]
#define FOFF_B1 200704UL
#define FOFF_B2 204800UL
#define FOFF_BOUT 208896UL                   // [128], pad zeroed
#define FOFF_CNT 209024UL                    // software grid-barrier counter (int)
#define PREP_TOTAL 21704896UL                // 21704704 + 128 bout + 64 counter area

__device__ __forceinline__ unsigned short f2bf(float f) {
  union { float f; unsigned u; } v; v.f = f;
  unsigned r = v.u + 0x7fffu + ((v.u >> 16) & 1u);  // RNE
  return (unsigned short)(r >> 16);
}
__device__ __forceinline__ float sigmoidf_(float x) {
  return 1.0f / (1.0f + __expf(-x));
}
// LDS bank swizzle: gbuf logical [gn][b] -> word index. Breaks the gn-major
// 16-way bank conflict on epilogue writes; update-phase reads stay stride-1.
__device__ __forceinline__ int sw(int gn, int b) {
  return gn * 64 + (b ^ ((gn & 7) << 2));
}

// Software grid barrier, monotonic counter (no reset; 515*194 < 2^31).
// Release: per-wave __threadfence (drain + L2 wb) before counting in.
// Acquire: per-wave __threadfence (L1/L2 inv) after the last block arrives.
__device__ __forceinline__ void gridbar(int* __restrict__ cnt, int target) {
  __threadfence();
  __syncthreads();          // all waves of this block have fenced their writes
  if (threadIdx.x == 0) {
    atomicAdd(cnt, 1);
    while (atomicAdd(cnt, 0) < target) __builtin_amdgcn_s_sleep(2);
  }
  __syncthreads();
  __threadfence();          // acquire in every wave: fresh reads after barrier
}

// ---------------- prep: bf16 weight conversion + zero/bias/counter init ----------------
__global__ void prep_kernel(const float* __restrict__ Whh0, const float* __restrict__ Wih1,
                            const float* __restrict__ Whh1, const float* __restrict__ Wih2,
                            const float* __restrict__ Whh2, const float* __restrict__ Wout,
                            const float* __restrict__ bih0, const float* __restrict__ bhh0,
                            const float* __restrict__ bih1, const float* __restrict__ bhh1,
                            const float* __restrict__ bih2, const float* __restrict__ bhh2,
                            const float* __restrict__ bout, void* wsv) {
  unsigned short* u = (unsigned short*)wsv;
  float* fr = (float*)((char*)wsv + FBYTE_BASE);
  size_t stride = (size_t)gridDim.x * blockDim.x;
  for (size_t i = (size_t)blockIdx.x * blockDim.x + threadIdx.x; i < PREP_TOTAL; i += stride) {
    if (i < 20971520UL) {                     // 5 big matrices, 2^22 elements each
      size_t which = i >> 22;
      size_t off = i & (M4 - 1UL);
      const float* src = (which == 0) ? Whh0 : (which == 1) ? Wih1 :
                         (which == 2) ? Whh1 : (which == 3) ? Wih2 : Whh2;
      u[i] = f2bf(src[off]);
    } else if (i < 21102592UL) {              // W_out -> 128x1024, pad rows zero
      size_t k = i - 20971520UL;
      size_t o = k >> 10, kk = k & 1023UL;
      u[i] = (o < 121) ? f2bf(Wout[o * 1024UL + kk]) : (unsigned short)0;
    } else if (i < 21495808UL) {              // h buffers zero (both parities)
      u[i] = 0;
    } else if (i < 21692416UL) {              // c zero
      fr[i - 21495808UL] = 0.0f;
    } else if (i < 21704704UL) {              // combined biases
      size_t k = i - 21692416UL;
      size_t l = k >> 12, n = k & 4095UL;
      const float* bi = (l == 0) ? bih0 : (l == 1) ? bih1 : bih2;
      const float* bh = (l == 0) ? bhh0 : (l == 1) ? bhh1 : bhh2;
      fr[FOFF_B0 + l * 4096UL + n] = bi[n] + bh[n];
    } else {                                  // bias_out pad + barrier counter (0 bits)
      size_t k = i - 21704704UL;
      fr[FOFF_BOUT + k] = (k < 121) ? bout[k] : 0.0f;
    }
  }
}

// ---------------- one LSTM layer step (one WG: 16 j-units x 4 gates x all 64 b) ----------------
// Waves split K 4 ways; partial gates reduced through LDS gbuf[4][64][64(sw)].
__device__ __forceinline__ void layer_step(
    int wgl, int tid, int t,
    const unsigned short* __restrict__ hin,    // [64][1024] bf16 at time t (null for layer 0)
    const unsigned short* __restrict__ hprev,  // [64][1024] bf16 own layer t-1
    unsigned short* __restrict__ hout,         // [64][1024] bf16 own layer t
    float* __restrict__ c,                     // [1024][64] fp32 (transposed)
    const unsigned short* __restrict__ Wih,    // bf16 [4096][1024] (null for layer 0)
    const unsigned short* __restrict__ Whh,    // bf16 [4096][1024]
    const float* __restrict__ bias,            // [4096] combined
    const float* __restrict__ strokes,         // layer 0 only
    const float* __restrict__ Wih0,            // layer 0 only, fp32 [4096][3]
    float* gbuf) {
  const int lane = tid & 63;
  const int w = tid >> 6;
  const int nl = lane & 15;
  const int kq8 = (lane >> 4) << 3;

  const unsigned short* A;
  const unsigned short* Wm;
  int k0beg, nk0;
  if (hin) {  // K = 2048: waves 0,1 -> input-proj halves; 2,3 -> recurrent halves
    A = (w < 2) ? hin : hprev;
    Wm = (w < 2) ? Wih : Whh;
    k0beg = (w & 1) * 512; nk0 = 16;
  } else {    // layer 0: K = 1024 recurrent only, quarter per wave
    A = hprev; Wm = Whh;
    k0beg = w * 256; nk0 = 8;
  }

  const unsigned short* wrow[4];
#pragma unroll
  for (int ns = 0; ns < 4; ++ns) {
    int jgl = wgl * 16 + ns * 4 + (nl >> 2);           // j handled by this lane
    int row = (nl & 3) * HD + jgl;                      // gate-major weight row
    wrow[ns] = Wm + (size_t)row * HD + kq8 + k0beg;
  }
  const unsigned short* arow = A + nl * HD + kq8 + k0beg;

  f32x4 acc[4][4];
  const f32x4 z4 = {0.f, 0.f, 0.f, 0.f};
#pragma unroll
  for (int ns = 0; ns < 4; ++ns)
#pragma unroll
    for (int mt = 0; mt < 4; ++mt) acc[ns][mt] = z4;

  for (int k = 0; k < nk0; ++k) {
    short8 bfr[4];
#pragma unroll
    for (int ns = 0; ns < 4; ++ns) bfr[ns] = *(const short8*)(wrow[ns] + k * 32);
#pragma unroll
    for (int mt = 0; mt < 4; ++mt) {
      short8 afr = *(const short8*)(arow + mt * 16 * HD + k * 32);
#pragma unroll
      for (int ns = 0; ns < 4; ++ns)
        acc[ns][mt] = __builtin_amdgcn_mfma_f32_16x16x32_bf16(afr, bfr[ns], acc[ns][mt], 0, 0, 0);
    }
  }

  // stash partial gates: slice w, logical [gn = ns*16+nl][b]
  float* gs = gbuf + w * 4096;
  const int bb = (lane >> 4) << 2;
#pragma unroll
  for (int ns = 0; ns < 4; ++ns) {
    int gn = ns * 16 + nl;
#pragma unroll
    for (int mt = 0; mt < 4; ++mt)
#pragma unroll
      for (int r = 0; r < 4; ++r)
        gs[sw(gn, mt * 16 + bb + r)] = acc[ns][mt][r];
  }
  __syncthreads();

  // reduce 4 K-slices + bias (+ strokes proj for layer 0), then LSTM cell update
#pragma unroll
  for (int it = 0; it < 4; ++it) {
    int item = it * 256 + tid;
    int jj = item >> 6;
    int b = item & 63;
    int j = wgl * 16 + jj;
    float p[4];
#pragma unroll
    for (int g = 0; g < 4; ++g) {
      int a = sw(jj * 4 + g, b);
      p[g] = gbuf[a] + gbuf[4096 + a] + gbuf[8192 + a] + gbuf[12288 + a] + bias[g * HD + j];
    }
    if (strokes) {
      const float* xr = strokes + ((size_t)b * TD + t) * 3;
      float x0 = xr[0], x1 = xr[1], x2 = xr[2];
#pragma unroll
      for (int g = 0; g < 4; ++g) {
        const float* wr = Wih0 + (size_t)(g * HD + j) * 3;
        p[g] += x0 * wr[0] + x1 * wr[1] + x2 * wr[2];
      }
    }
    float iv = sigmoidf_(p[0]);
    float fv = sigmoidf_(p[1]);
    float gv = tanhf(p[2]);
    float ov = sigmoidf_(p[3]);
    int ci = j * BD + b;  // transposed c -> coalesced RMW
    float cn = fv * c[ci] + iv * gv;
    c[ci] = cn;
    hout[(size_t)b * HD + j] = f2bf(ov * tanhf(cn));
  }
}

// ---------------- output projection step (2 WGs: 64 o-columns each) ----------------
__device__ __forceinline__ void out_step(
    int wgo, int tid, int t,
    const unsigned short* __restrict__ h2,  // [64][1024] bf16 at time t
    const unsigned short* __restrict__ Wo,  // bf16 [128][1024] padded
    const float* __restrict__ bo,           // [128] padded
    float* __restrict__ outp,               // [64][512][121] fp32
    float* gbuf) {
  const int lane = tid & 63;
  const int w = tid >> 6;
  const int nl = lane & 15;
  const int kq8 = (lane >> 4) << 3;
  const int k0beg = w * 256;

  const unsigned short* wrow[4];
#pragma unroll
  for (int ns = 0; ns < 4; ++ns) {
    int o = wgo * 64 + ns * 16 + nl;
    wrow[ns] = Wo + (size_t)o * HD + kq8 + k0beg;
  }
  const unsigned short* arow = h2 + nl * HD + kq8 + k0beg;

  f32x4 acc[4][4];
  const f32x4 z4 = {0.f, 0.f, 0.f, 0.f};
#pragma unroll
  for (int ns = 0; ns < 4; ++ns)
#pragma unroll
    for (int mt = 0; mt < 4; ++mt) acc[ns][mt] = z4;

  for (int k = 0; k < 8; ++k) {
    short8 bfr[4];
#pragma unroll
    for (int ns = 0; ns < 4; ++ns) bfr[ns] = *(const short8*)(wrow[ns] + k * 32);
#pragma unroll
    for (int mt = 0; mt < 4; ++mt) {
      short8 afr = *(const short8*)(arow + mt * 16 * HD + k * 32);
#pragma unroll
      for (int ns = 0; ns < 4; ++ns)
        acc[ns][mt] = __builtin_amdgcn_mfma_f32_16x16x32_bf16(afr, bfr[ns], acc[ns][mt], 0, 0, 0);
    }
  }

  float* gs = gbuf + w * 4096;
  const int bb = (lane >> 4) << 2;
#pragma unroll
  for (int ns = 0; ns < 4; ++ns) {
    int gn = ns * 16 + nl;
#pragma unroll
    for (int mt = 0; mt < 4; ++mt)
#pragma unroll
      for (int r = 0; r < 4; ++r)
        gs[sw(gn, mt * 16 + bb + r)] = acc[ns][mt][r];
  }
  __syncthreads();

#pragma unroll
  for (int it = 0; it < 16; ++it) {
    int item = it * 256 + tid;
    int ol = item >> 6;
    int b = item & 63;
    int o = wgo * 64 + ol;
    int a = sw(ol, b);
    float v = gbuf[a] + gbuf[4096 + a] + gbuf[8192 + a] + gbuf[12288 + a] + bo[o];
    if (o < 121) outp[((size_t)b * TD + t) * 121 + o] = v;
  }
}

// ---------------- main kernel: wavefront over layers, software grid barrier ----------------
// WGs 0..63 layer0, 64..127 layer1, 128..191 layer2, 192..193 out-proj.
// Plain launch (NOT cooperative). Deadlock-safe: 194 blocks <= 256 CUs and
// per-CU capacity >= 1 at 64KB LDS / 4 waves, so all blocks co-resident.
__global__ void __launch_bounds__(256, 1)
lstm_main(const float* __restrict__ strokes, const float* __restrict__ Wih0,
          float* __restrict__ outp, void* __restrict__ wsv) {
  __shared__ float gbuf[16384];  // 64 KB: 4 K-slices x [64 gn][64 b]
  unsigned short* u = (unsigned short*)wsv;
  float* fr = (float*)((char*)wsv + FBYTE_BASE);

  const unsigned short* Whh0 = u + OFF_WHH0;
  const unsigned short* Wih1 = u + OFF_WIH1;
  const unsigned short* Whh1 = u + OFF_WHH1;
  const unsigned short* Wih2 = u + OFF_WIH2;
  const unsigned short* Whh2 = u + OFF_WHH2;
  const unsigned short* Wout = u + OFF_WOUT;
  unsigned short* h0 = u + OFF_H0;
  unsigned short* h1 = u + OFF_H1;
  unsigned short* h2 = u + OFF_H2;
  float* c0 = fr + FOFF_C0;
  float* c1 = fr + FOFF_C1;
  float* c2 = fr + FOFF_C2;
  const float* b0 = fr + FOFF_B0;
  const float* b1 = fr + FOFF_B1;
  const float* b2 = fr + FOFF_B2;
  const float* bo = fr + FOFF_BOUT;
  int* cnt = (int*)(fr + FOFF_CNT);

  const int wg = blockIdx.x;
  const int tid = threadIdx.x;

  for (int s = 0; s < TD + 3; ++s) {
    if (wg < 64) {
      int t = s;
      if (t < TD)
        layer_step(wg, tid, t, nullptr,
                   h0 + (size_t)((t - 1) & 1) * BH, h0 + (size_t)(t & 1) * BH, c0,
                   nullptr, Whh0, b0, strokes, Wih0, gbuf);
    } else if (wg < 128) {
      int t = s - 1;
      if (t >= 0 && t < TD)
        layer_step(wg - 64, tid, t, h0 + (size_t)(t & 1) * BH,
                   h1 + (size_t)((t - 1) & 1) * BH, h1 + (size_t)(t & 1) * BH, c1,
                   Wih1, Whh1, b1, nullptr, nullptr, gbuf);
    } else if (wg < 192) {
      int t = s - 2;
      if (t >= 0 && t < TD)
        layer_step(wg - 128, tid, t, h1 + (size_t)(t & 1) * BH,
                   h2 + (size_t)((t - 1) & 1) * BH, h2 + (size_t)(t & 1) * BH, c2,
                   Wih2, Whh2, b2, nullptr, nullptr, gbuf);
    } else {
      int t = s - 3;
      if (t >= 0 && t < TD)
        out_step(wg - 192, tid, t, h2 + (size_t)(t & 1) * BH, Wout, bo, outp, gbuf);
    }
    gridbar(cnt, (s + 1) * NBLK);
  }
}

extern "C" void kernel_launch(void* const* d_in, const int* in_sizes, int n_in,
                              void* d_out, int out_size, void* d_ws, size_t ws_size,
                              hipStream_t stream) {
  const float* strokes = (const float*)d_in[0];
  const float* Wih0 = (const float*)d_in[1];
  const float* Whh0 = (const float*)d_in[2];
  const float* bih0 = (const float*)d_in[3];
  const float* bhh0 = (const float*)d_in[4];
  const float* Wih1 = (const float*)d_in[5];
  const float* Whh1 = (const float*)d_in[6];
  const float* bih1 = (const float*)d_in[7];
  const float* bhh1 = (const float*)d_in[8];
  const float* Wih2 = (const float*)d_in[9];
  const float* Whh2 = (const float*)d_in[10];
  const float* bih2 = (const float*)d_in[11];
  const float* bhh2 = (const float*)d_in[12];
  const float* Wout = (const float*)d_in[13];
  const float* bout = (const float*)d_in[14];
  float* outp = (float*)d_out;

  hipLaunchKernelGGL(prep_kernel, dim3(4096), dim3(256), 0, stream,
                     Whh0, Wih1, Whh1, Wih2, Whh2, Wout,
                     bih0, bhh0, bih1, bhh1, bih2, bhh2, bout, d_ws);

  hipLaunchKernelGGL(lstm_main, dim3(NBLK), dim3(256), 0, stream,
                     strokes, Wih0, outp, d_ws);
}

// Round 3
// 16491.324 us; speedup vs baseline: 1.9966x; 1.9966x over previous
//
#include <hip/hip_runtime.h>

typedef __attribute__((ext_vector_type(8))) short short8;
typedef __attribute__((ext_vector_type(4))) float f32x4;

#define HD 1024
#define BD 64
#define TD 512
#define BH 65536UL  // 64*1024
#define NBLK 194

// ---------------- workspace layout ----------------
// ushort (bf16) region first, then float region. All offsets in elements.
#define M4 4194304UL
#define OFF_WHH0 0UL
#define OFF_WIH1 (1UL * M4)
#define OFF_WHH1 (2UL * M4)
#define OFF_WIH2 (3UL * M4)
#define OFF_WHH2 (4UL * M4)
#define OFF_WOUT (5UL * M4)                 // 128 x 1024 (padded rows zeroed)
#define OFF_H0   (OFF_WOUT + 131072UL)      // [2][64][1024] each
#define OFF_H1   (OFF_H0 + 131072UL)
#define OFF_H2   (OFF_H1 + 131072UL)
#define USHORT_TOTAL (OFF_H2 + 131072UL)    // 21,495,808 ushorts
#define FBYTE_BASE (USHORT_TOTAL * 2UL)     // byte offset of float region (16B aligned)
#define FOFF_C0 0UL                          // c stored [j][b] (transposed)
#define FOFF_C1 65536UL
#define FOFF_C2 131072UL
#define FOFF_B0 196608UL                     // combined biases b_ih+b_hh [4096]
#define FOFF_B1 200704UL
#define FOFF_B2 204800UL
#define FOFF_BOUT 208896UL                   // [128], pad zeroed
#define FOFF_CNT 209024UL                    // software grid-barrier counter (int)
#define PREP_TOTAL 21704896UL

__device__ __forceinline__ unsigned short f2bf(float f) {
  union { float f; unsigned u; } v; v.f = f;
  unsigned r = v.u + 0x7fffu + ((v.u >> 16) & 1u);  // RNE
  return (unsigned short)(r >> 16);
}
__device__ __forceinline__ float sigmoidf_(float x) {
  return 1.0f / (1.0f + __expf(-x));
}
// LDS bank swizzle: gbuf logical [gn][b] -> word index.
__device__ __forceinline__ int sw(int gn, int b) {
  return gn * 64 + (b ^ ((gn & 7) << 2));
}

// Agent-scope (coherence-point) 16B h-fragment load: bypasses non-coherent
// L1/L2 so cross-XCD h writes are always seen fresh. Relaxed -> no waitcnt
// forced between consecutive loads; they pipeline.
__device__ __forceinline__ short8 load_h16(const unsigned short* p) {
  union { unsigned long long q[2]; short8 v; } u;
  u.q[0] = __hip_atomic_load((const unsigned long long*)p, __ATOMIC_RELAXED,
                             __HIP_MEMORY_SCOPE_AGENT);
  u.q[1] = __hip_atomic_load(((const unsigned long long*)p) + 1, __ATOMIC_RELAXED,
                             __HIP_MEMORY_SCOPE_AGENT);
  return u.v;
}

// Software grid barrier, monotonic counter (515*194 < 2^31). Fence-free:
// all cross-XCD payload (h, counter) moves through agent-scope bypass ops,
// so no buffer_wbl2/buffer_inv is needed -- weights stay L2-resident.
// Each wave drains vmcnt (h write-through stores retired at coherence point)
// before the block barrier; thread0 then counts in and polls with plain
// agent-scope loads (no RMW ping-pong).
__device__ __forceinline__ void gridbar(int* cnt, int target) {
  asm volatile("s_waitcnt vmcnt(0)" ::: "memory");
  __syncthreads();
  if (threadIdx.x == 0) {
    __hip_atomic_fetch_add(cnt, 1, __ATOMIC_RELAXED, __HIP_MEMORY_SCOPE_AGENT);
    while (__hip_atomic_load(cnt, __ATOMIC_RELAXED, __HIP_MEMORY_SCOPE_AGENT) < target)
      __builtin_amdgcn_s_sleep(2);
  }
  __syncthreads();
}

// ---------------- prep: bf16 weight conversion + zero/bias/counter init ----------------
__global__ void prep_kernel(const float* __restrict__ Whh0, const float* __restrict__ Wih1,
                            const float* __restrict__ Whh1, const float* __restrict__ Wih2,
                            const float* __restrict__ Whh2, const float* __restrict__ Wout,
                            const float* __restrict__ bih0, const float* __restrict__ bhh0,
                            const float* __restrict__ bih1, const float* __restrict__ bhh1,
                            const float* __restrict__ bih2, const float* __restrict__ bhh2,
                            const float* __restrict__ bout, void* wsv) {
  unsigned short* u = (unsigned short*)wsv;
  float* fr = (float*)((char*)wsv + FBYTE_BASE);
  size_t stride = (size_t)gridDim.x * blockDim.x;
  for (size_t i = (size_t)blockIdx.x * blockDim.x + threadIdx.x; i < PREP_TOTAL; i += stride) {
    if (i < 20971520UL) {                     // 5 big matrices, 2^22 elements each
      size_t which = i >> 22;
      size_t off = i & (M4 - 1UL);
      const float* src = (which == 0) ? Whh0 : (which == 1) ? Wih1 :
                         (which == 2) ? Whh1 : (which == 3) ? Wih2 : Whh2;
      u[i] = f2bf(src[off]);
    } else if (i < 21102592UL) {              // W_out -> 128x1024, pad rows zero
      size_t k = i - 20971520UL;
      size_t o = k >> 10, kk = k & 1023UL;
      u[i] = (o < 121) ? f2bf(Wout[o * 1024UL + kk]) : (unsigned short)0;
    } else if (i < 21495808UL) {              // h buffers zero (both parities)
      u[i] = 0;
    } else if (i < 21692416UL) {              // c zero
      fr[i - 21495808UL] = 0.0f;
    } else if (i < 21704704UL) {              // combined biases
      size_t k = i - 21692416UL;
      size_t l = k >> 12, n = k & 4095UL;
      const float* bi = (l == 0) ? bih0 : (l == 1) ? bih1 : bih2;
      const float* bh = (l == 0) ? bhh0 : (l == 1) ? bhh1 : bhh2;
      fr[FOFF_B0 + l * 4096UL + n] = bi[n] + bh[n];
    } else {                                  // bias_out pad + barrier counter (0 bits)
      size_t k = i - 21704704UL;
      fr[FOFF_BOUT + k] = (k < 121) ? bout[k] : 0.0f;
    }
  }
}

// ---------------- one LSTM layer step (one WG: 16 j-units x 4 gates x all 64 b) ----------------
// Waves split K 4 ways; partial gates reduced through LDS gbuf[4][64][64(sw)].
__device__ __forceinline__ void layer_step(
    int wgl, int tid, int t,
    const unsigned short* __restrict__ hin,    // [64][1024] bf16 at time t (null for layer 0)
    const unsigned short* __restrict__ hprev,  // [64][1024] bf16 own layer t-1
    unsigned short* __restrict__ hout,         // [64][1024] bf16 own layer t
    float* __restrict__ c,                     // [1024][64] fp32 (transposed)
    const unsigned short* __restrict__ Wih,    // bf16 [4096][1024] (null for layer 0)
    const unsigned short* __restrict__ Whh,    // bf16 [4096][1024]
    const float* __restrict__ bias,            // [4096] combined
    const float* __restrict__ strokes,         // layer 0 only
    const float* __restrict__ Wih0,            // layer 0 only, fp32 [4096][3]
    float* gbuf) {
  const int lane = tid & 63;
  const int w = tid >> 6;
  const int nl = lane & 15;
  const int kq8 = (lane >> 4) << 3;

  const unsigned short* A;
  const unsigned short* Wm;
  int k0beg, nk0;
  if (hin) {  // K = 2048: waves 0,1 -> input-proj halves; 2,3 -> recurrent halves
    A = (w < 2) ? hin : hprev;
    Wm = (w < 2) ? Wih : Whh;
    k0beg = (w & 1) * 512; nk0 = 16;
  } else {    // layer 0: K = 1024 recurrent only, quarter per wave
    A = hprev; Wm = Whh;
    k0beg = w * 256; nk0 = 8;
  }

  const unsigned short* wrow[4];
#pragma unroll
  for (int ns = 0; ns < 4; ++ns) {
    int jgl = wgl * 16 + ns * 4 + (nl >> 2);           // j handled by this lane
    int row = (nl & 3) * HD + jgl;                      // gate-major weight row
    wrow[ns] = Wm + (size_t)row * HD + kq8 + k0beg;
  }
  const unsigned short* arow = A + nl * HD + kq8 + k0beg;

  f32x4 acc[4][4];
  const f32x4 z4 = {0.f, 0.f, 0.f, 0.f};
#pragma unroll
  for (int ns = 0; ns < 4; ++ns)
#pragma unroll
    for (int mt = 0; mt < 4; ++mt) acc[ns][mt] = z4;

  for (int k = 0; k < nk0; ++k) {
    short8 afr[4];
#pragma unroll
    for (int mt = 0; mt < 4; ++mt) afr[mt] = load_h16(arow + mt * 16 * HD + k * 32);
    short8 bfr[4];
#pragma unroll
    for (int ns = 0; ns < 4; ++ns) bfr[ns] = *(const short8*)(wrow[ns] + k * 32);
#pragma unroll
    for (int mt = 0; mt < 4; ++mt)
#pragma unroll
      for (int ns = 0; ns < 4; ++ns)
        acc[ns][mt] = __builtin_amdgcn_mfma_f32_16x16x32_bf16(afr[mt], bfr[ns], acc[ns][mt], 0, 0, 0);
  }

  // stash partial gates: slice w, logical [gn = ns*16+nl][b]
  float* gs = gbuf + w * 4096;
  const int bb = (lane >> 4) << 2;
#pragma unroll
  for (int ns = 0; ns < 4; ++ns) {
    int gn = ns * 16 + nl;
#pragma unroll
    for (int mt = 0; mt < 4; ++mt)
#pragma unroll
      for (int r = 0; r < 4; ++r)
        gs[sw(gn, mt * 16 + bb + r)] = acc[ns][mt][r];
  }
  __syncthreads();

  // reduce 4 K-slices + bias (+ strokes proj for layer 0), then LSTM cell update.
  // Paired over adjacent j so the h write is one 4-byte agent-scope store.
#pragma unroll
  for (int it = 0; it < 2; ++it) {
    int item = it * 256 + tid;
    int jp = item >> 6;            // 0..7 (pair of j)
    int b = item & 63;
    unsigned hv[2];
#pragma unroll
    for (int u2 = 0; u2 < 2; ++u2) {
      int jj = jp * 2 + u2;
      int j = wgl * 16 + jj;
      float p[4];
#pragma unroll
      for (int g = 0; g < 4; ++g) {
        int a = sw(jj * 4 + g, b);
        p[g] = gbuf[a] + gbuf[4096 + a] + gbuf[8192 + a] + gbuf[12288 + a] + bias[g * HD + j];
      }
      if (strokes) {
        const float* xr = strokes + ((size_t)b * TD + t) * 3;
        float x0 = xr[0], x1 = xr[1], x2 = xr[2];
#pragma unroll
        for (int g = 0; g < 4; ++g) {
          const float* wr = Wih0 + (size_t)(g * HD + j) * 3;
          p[g] += x0 * wr[0] + x1 * wr[1] + x2 * wr[2];
        }
      }
      float iv = sigmoidf_(p[0]);
      float fv = sigmoidf_(p[1]);
      float gv = tanhf(p[2]);
      float ov = sigmoidf_(p[3]);
      int ci = j * BD + b;  // transposed c -> coalesced RMW, CU-private, normal cache
      float cn = fv * c[ci] + iv * gv;
      c[ci] = cn;
      hv[u2] = (unsigned)f2bf(ov * tanhf(cn));
    }
    unsigned packed = hv[0] | (hv[1] << 16);
    __hip_atomic_store((unsigned*)(hout + (size_t)b * HD + wgl * 16 + jp * 2), packed,
                       __ATOMIC_RELAXED, __HIP_MEMORY_SCOPE_AGENT);
  }
}

// ---------------- output projection step (2 WGs: 64 o-columns each) ----------------
__device__ __forceinline__ void out_step(
    int wgo, int tid, int t,
    const unsigned short* __restrict__ h2,  // [64][1024] bf16 at time t
    const unsigned short* __restrict__ Wo,  // bf16 [128][1024] padded
    const float* __restrict__ bo,           // [128] padded
    float* __restrict__ outp,               // [64][512][121] fp32
    float* gbuf) {
  const int lane = tid & 63;
  const int w = tid >> 6;
  const int nl = lane & 15;
  const int kq8 = (lane >> 4) << 3;
  const int k0beg = w * 256;

  const unsigned short* wrow[4];
#pragma unroll
  for (int ns = 0; ns < 4; ++ns) {
    int o = wgo * 64 + ns * 16 + nl;
    wrow[ns] = Wo + (size_t)o * HD + kq8 + k0beg;
  }
  const unsigned short* arow = h2 + nl * HD + kq8 + k0beg;

  f32x4 acc[4][4];
  const f32x4 z4 = {0.f, 0.f, 0.f, 0.f};
#pragma unroll
  for (int ns = 0; ns < 4; ++ns)
#pragma unroll
    for (int mt = 0; mt < 4; ++mt) acc[ns][mt] = z4;

  for (int k = 0; k < 8; ++k) {
    short8 afr[4];
#pragma unroll
    for (int mt = 0; mt < 4; ++mt) afr[mt] = load_h16(arow + mt * 16 * HD + k * 32);
    short8 bfr[4];
#pragma unroll
    for (int ns = 0; ns < 4; ++ns) bfr[ns] = *(const short8*)(wrow[ns] + k * 32);
#pragma unroll
    for (int mt = 0; mt < 4; ++mt)
#pragma unroll
      for (int ns = 0; ns < 4; ++ns)
        acc[ns][mt] = __builtin_amdgcn_mfma_f32_16x16x32_bf16(afr[mt], bfr[ns], acc[ns][mt], 0, 0, 0);
  }

  float* gs = gbuf + w * 4096;
  const int bb = (lane >> 4) << 2;
#pragma unroll
  for (int ns = 0; ns < 4; ++ns) {
    int gn = ns * 16 + nl;
#pragma unroll
    for (int mt = 0; mt < 4; ++mt)
#pragma unroll
      for (int r = 0; r < 4; ++r)
        gs[sw(gn, mt * 16 + bb + r)] = acc[ns][mt][r];
  }
  __syncthreads();

#pragma unroll
  for (int it = 0; it < 16; ++it) {
    int item = it * 256 + tid;
    int ol = item >> 6;
    int b = item & 63;
    int o = wgo * 64 + ol;
    int a = sw(ol, b);
    float v = gbuf[a] + gbuf[4096 + a] + gbuf[8192 + a] + gbuf[12288 + a] + bo[o];
    if (o < 121) outp[((size_t)b * TD + t) * 121 + o] = v;  // normal store; kernel-end flush
  }
}

// ---------------- main kernel: wavefront over layers, software grid barrier ----------------
// WGs 0..63 layer0, 64..127 layer1, 128..191 layer2, 192..193 out-proj.
// Plain launch. Deadlock-safe: 194 blocks <= 256 CUs, 1 block/CU resident.
__global__ void __launch_bounds__(256, 1)
lstm_main(const float* __restrict__ strokes, const float* __restrict__ Wih0,
          float* __restrict__ outp, void* __restrict__ wsv) {
  __shared__ float gbuf[16384];  // 64 KB: 4 K-slices x [64 gn][64 b]
  unsigned short* u = (unsigned short*)wsv;
  float* fr = (float*)((char*)wsv + FBYTE_BASE);

  const unsigned short* Whh0 = u + OFF_WHH0;
  const unsigned short* Wih1 = u + OFF_WIH1;
  const unsigned short* Whh1 = u + OFF_WHH1;
  const unsigned short* Wih2 = u + OFF_WIH2;
  const unsigned short* Whh2 = u + OFF_WHH2;
  const unsigned short* Wout = u + OFF_WOUT;
  unsigned short* h0 = u + OFF_H0;
  unsigned short* h1 = u + OFF_H1;
  unsigned short* h2 = u + OFF_H2;
  float* c0 = fr + FOFF_C0;
  float* c1 = fr + FOFF_C1;
  float* c2 = fr + FOFF_C2;
  const float* b0 = fr + FOFF_B0;
  const float* b1 = fr + FOFF_B1;
  const float* b2 = fr + FOFF_B2;
  const float* bo = fr + FOFF_BOUT;
  int* cnt = (int*)(fr + FOFF_CNT);

  const int wg = blockIdx.x;
  const int tid = threadIdx.x;

  for (int s = 0; s < TD + 3; ++s) {
    if (wg < 64) {
      int t = s;
      if (t < TD)
        layer_step(wg, tid, t, nullptr,
                   h0 + (size_t)((t - 1) & 1) * BH, h0 + (size_t)(t & 1) * BH, c0,
                   nullptr, Whh0, b0, strokes, Wih0, gbuf);
    } else if (wg < 128) {
      int t = s - 1;
      if (t >= 0 && t < TD)
        layer_step(wg - 64, tid, t, h0 + (size_t)(t & 1) * BH,
                   h1 + (size_t)((t - 1) & 1) * BH, h1 + (size_t)(t & 1) * BH, c1,
                   Wih1, Whh1, b1, nullptr, nullptr, gbuf);
    } else if (wg < 192) {
      int t = s - 2;
      if (t >= 0 && t < TD)
        layer_step(wg - 128, tid, t, h1 + (size_t)(t & 1) * BH,
                   h2 + (size_t)((t - 1) & 1) * BH, h2 + (size_t)(t & 1) * BH, c2,
                   Wih2, Whh2, b2, nullptr, nullptr, gbuf);
    } else {
      int t = s - 3;
      if (t >= 0 && t < TD)
        out_step(wg - 192, tid, t, h2 + (size_t)(t & 1) * BH, Wout, bo, outp, gbuf);
    }
    gridbar(cnt, (s + 1) * NBLK);
  }
}

extern "C" void kernel_launch(void* const* d_in, const int* in_sizes, int n_in,
                              void* d_out, int out_size, void* d_ws, size_t ws_size,
                              hipStream_t stream) {
  const float* strokes = (const float*)d_in[0];
  const float* Wih0 = (const float*)d_in[1];
  const float* Whh0 = (const float*)d_in[2];
  const float* bih0 = (const float*)d_in[3];
  const float* bhh0 = (const float*)d_in[4];
  const float* Wih1 = (const float*)d_in[5];
  const float* Whh1 = (const float*)d_in[6];
  const float* bih1 = (const float*)d_in[7];
  const float* bhh1 = (const float*)d_in[8];
  const float* Wih2 = (const float*)d_in[9];
  const float* Whh2 = (const float*)d_in[10];
  const float* bih2 = (const float*)d_in[11];
  const float* bhh2 = (const float*)d_in[12];
  const float* Wout = (const float*)d_in[13];
  const float* bout = (const float*)d_in[14];
  float* outp = (float*)d_out;

  hipLaunchKernelGGL(prep_kernel, dim3(4096), dim3(256), 0, stream,
                     Whh0, Wih1, Whh1, Wih2, Whh2, Wout,
                     bih0, bhh0, bih1, bhh1, bih2, bhh2, bout, d_ws);

  hipLaunchKernelGGL(lstm_main, dim3(NBLK), dim3(256), 0, stream,
                     strokes, Wih0, outp, d_ws);
}

// Round 4
// 12498.683 us; speedup vs baseline: 2.6344x; 1.3194x over previous
//
#include <hip/hip_runtime.h>

typedef __attribute__((ext_vector_type(8))) short short8;
typedef __attribute__((ext_vector_type(4))) float f32x4;

#define HD 1024
#define BD 64
#define TD 512
#define BH 65536UL  // 64*1024
#define NBLK 194

// ---------------- workspace layout ----------------
#define M4 4194304UL
#define OFF_WHH0 0UL
#define OFF_WIH1 (1UL * M4)
#define OFF_WHH1 (2UL * M4)
#define OFF_WIH2 (3UL * M4)
#define OFF_WHH2 (4UL * M4)
#define OFF_WOUT (5UL * M4)                 // 128 x 1024 (padded rows zeroed)
#define OFF_H0   (OFF_WOUT + 131072UL)      // [2][64][1024] each
#define OFF_H1   (OFF_H0 + 131072UL)
#define OFF_H2   (OFF_H1 + 131072UL)
#define USHORT_TOTAL (OFF_H2 + 131072UL)
#define FBYTE_BASE (USHORT_TOTAL * 2UL)
#define FOFF_C0 0UL                          // c stored [j][b] (transposed)
#define FOFF_C1 65536UL
#define FOFF_C2 131072UL
#define FOFF_B0 196608UL                     // combined biases b_ih+b_hh [4096]
#define FOFF_B1 200704UL
#define FOFF_B2 204800UL
#define FOFF_BOUT 208896UL                   // [128], pad zeroed
#define FOFF_CNT 209024UL                    // software grid-barrier counter
#define PREP_TOTAL 21704896UL

__device__ __forceinline__ unsigned short f2bf(float f) {
  union { float f; unsigned u; } v; v.f = f;
  unsigned r = v.u + 0x7fffu + ((v.u >> 16) & 1u);  // RNE
  return (unsigned short)(r >> 16);
}
__device__ __forceinline__ float sigmoidf_(float x) {
  return 1.0f / (1.0f + __expf(-x));
}
__device__ __forceinline__ int sw(int gn, int b) {
  return gn * 64 + (b ^ ((gn & 7) << 2));
}

// Agent-scope bypass 16B h-fragment load (fresh across XCDs, no fences needed).
__device__ __forceinline__ short8 load_h16(const unsigned short* p) {
  union { unsigned long long q[2]; short8 v; } u;
  u.q[0] = __hip_atomic_load((const unsigned long long*)p, __ATOMIC_RELAXED,
                             __HIP_MEMORY_SCOPE_AGENT);
  u.q[1] = __hip_atomic_load(((const unsigned long long*)p) + 1, __ATOMIC_RELAXED,
                             __HIP_MEMORY_SCOPE_AGENT);
  return u.v;
}

// Fence-free software grid barrier (monotonic counter; 515*194 < 2^31).
__device__ __forceinline__ void gridbar(int* cnt, int target) {
  asm volatile("s_waitcnt vmcnt(0)" ::: "memory");  // h write-through retired
  __syncthreads();
  if (threadIdx.x == 0) {
    __hip_atomic_fetch_add(cnt, 1, __ATOMIC_RELAXED, __HIP_MEMORY_SCOPE_AGENT);
    while (__hip_atomic_load(cnt, __ATOMIC_RELAXED, __HIP_MEMORY_SCOPE_AGENT) < target)
      __builtin_amdgcn_s_sleep(1);
  }
  __syncthreads();
}

// ---------------- prep ----------------
__global__ void prep_kernel(const float* __restrict__ Whh0, const float* __restrict__ Wih1,
                            const float* __restrict__ Whh1, const float* __restrict__ Wih2,
                            const float* __restrict__ Whh2, const float* __restrict__ Wout,
                            const float* __restrict__ bih0, const float* __restrict__ bhh0,
                            const float* __restrict__ bih1, const float* __restrict__ bhh1,
                            const float* __restrict__ bih2, const float* __restrict__ bhh2,
                            const float* __restrict__ bout, void* wsv) {
  unsigned short* u = (unsigned short*)wsv;
  float* fr = (float*)((char*)wsv + FBYTE_BASE);
  size_t stride = (size_t)gridDim.x * blockDim.x;
  for (size_t i = (size_t)blockIdx.x * blockDim.x + threadIdx.x; i < PREP_TOTAL; i += stride) {
    if (i < 20971520UL) {
      size_t which = i >> 22;
      size_t off = i & (M4 - 1UL);
      const float* src = (which == 0) ? Whh0 : (which == 1) ? Wih1 :
                         (which == 2) ? Whh1 : (which == 3) ? Wih2 : Whh2;
      u[i] = f2bf(src[off]);
    } else if (i < 21102592UL) {
      size_t k = i - 20971520UL;
      size_t o = k >> 10, kk = k & 1023UL;
      u[i] = (o < 121) ? f2bf(Wout[o * 1024UL + kk]) : (unsigned short)0;
    } else if (i < 21495808UL) {
      u[i] = 0;
    } else if (i < 21692416UL) {
      fr[i - 21495808UL] = 0.0f;
    } else if (i < 21704704UL) {
      size_t k = i - 21692416UL;
      size_t l = k >> 12, n = k & 4095UL;
      const float* bi = (l == 0) ? bih0 : (l == 1) ? bih1 : bih2;
      const float* bh = (l == 0) ? bhh0 : (l == 1) ? bhh1 : bhh2;
      fr[FOFF_B0 + l * 4096UL + n] = bi[n] + bh[n];
    } else {
      size_t k = i - 21704704UL;
      fr[FOFF_BOUT + k] = (k < 121) ? bout[k] : 0.0f;
    }
  }
}

// ---------------- GEMM slice: register-resident B, depth-3 pipelined bypass A ----------------
template <int NK>
__device__ __forceinline__ void gemm_bw(const unsigned short* __restrict__ arow,
                                        const short8 (&bw)[NK][4],
                                        f32x4 (&acc)[4][4]) {
  short8 ab[3][4];
#pragma unroll
  for (int p = 0; p < 3; ++p)
#pragma unroll
    for (int mt = 0; mt < 4; ++mt)
      ab[p][mt] = load_h16(arow + mt * 16 * HD + p * 32);
#pragma unroll
  for (int k = 0; k < NK; ++k) {
    const int slot = k % 3;
#pragma unroll
    for (int mt = 0; mt < 4; ++mt) {
      const short8 a = ab[slot][mt];
#pragma unroll
      for (int ns = 0; ns < 4; ++ns)
        acc[ns][mt] = __builtin_amdgcn_mfma_f32_16x16x32_bf16(a, bw[k][ns], acc[ns][mt], 0, 0, 0);
    }
    if (k + 3 < NK) {
#pragma unroll
      for (int mt = 0; mt < 4; ++mt)
        ab[slot][mt] = load_h16(arow + mt * 16 * HD + (k + 3) * 32);
    }
  }
}

// ---------------- persistent-weight layer driver ----------------
// One WG: 16 j-units x 4 gates x all 64 b. Waves split K 4 ways; partials
// reduced through LDS gbuf[4][64][64(sw)]. B-fragments live in VGPRs for the
// whole kernel (occupancy is LDS-pinned at 1 block/CU, so <=512 VGPR is free).
template <bool L0>
__device__ __forceinline__ void run_layer(
    int wgl, int tid, int delay,
    const unsigned short* __restrict__ hinbase,  // upstream h (both parities), null for L0
    unsigned short* __restrict__ hbase,          // own h (both parities)
    float* __restrict__ c,                       // [1024][64] fp32 transposed
    const unsigned short* __restrict__ Wih,      // null for L0
    const unsigned short* __restrict__ Whh,
    const float* __restrict__ bias,
    const float* __restrict__ strokes,           // L0 only
    const float* __restrict__ Wih0,              // L0 only, fp32 [4096][3]
    float* gbuf, int* cnt) {
  constexpr int NK = L0 ? 8 : 16;
  const int lane = tid & 63;
  const int w = tid >> 6;
  const int nl = lane & 15;
  const int kq8 = (lane >> 4) << 3;

  const unsigned short* Wm;
  int k0beg;
  bool useHin;
  if (L0) { Wm = Whh; k0beg = w * 256; useHin = false; }
  else    { Wm = (w < 2) ? Wih : Whh; k0beg = (w & 1) * 512; useHin = (w < 2); }

  short8 bw[NK][4];
#pragma unroll
  for (int ns = 0; ns < 4; ++ns) {
    int jgl = wgl * 16 + ns * 4 + (nl >> 2);
    int row = (nl & 3) * HD + jgl;                 // gate-major weight row
    const unsigned short* wr = Wm + (size_t)row * HD + kq8 + k0beg;
#pragma unroll
    for (int k = 0; k < NK; ++k) bw[k][ns] = *(const short8*)(wr + k * 32);
  }

  const int bb = (lane >> 4) << 2;
  float* gs = gbuf + w * 4096;

  for (int s = 0; s < TD + 3; ++s) {
    int t = s - delay;
    if (t >= 0 && t < TD) {
      const unsigned short* A = useHin ? (hinbase + (size_t)(t & 1) * BH)
                                       : (hbase + (size_t)((t - 1) & 1) * BH);
      const unsigned short* arow = A + nl * HD + kq8 + k0beg;

      f32x4 acc[4][4];
      const f32x4 z4 = {0.f, 0.f, 0.f, 0.f};
#pragma unroll
      for (int ns = 0; ns < 4; ++ns)
#pragma unroll
        for (int mt = 0; mt < 4; ++mt) acc[ns][mt] = z4;

      gemm_bw<NK>(arow, bw, acc);

#pragma unroll
      for (int ns = 0; ns < 4; ++ns) {
        int gn = ns * 16 + nl;
#pragma unroll
        for (int mt = 0; mt < 4; ++mt)
#pragma unroll
          for (int r = 0; r < 4; ++r)
            gs[sw(gn, mt * 16 + bb + r)] = acc[ns][mt][r];
      }
      __syncthreads();

      unsigned short* hout = hbase + (size_t)(t & 1) * BH;
#pragma unroll
      for (int it = 0; it < 2; ++it) {
        int item = it * 256 + tid;
        int jp = item >> 6;          // 0..7 pair of j
        int b = item & 63;
        unsigned hv[2];
#pragma unroll
        for (int u2 = 0; u2 < 2; ++u2) {
          int jj = jp * 2 + u2;
          int j = wgl * 16 + jj;
          float p[4];
#pragma unroll
          for (int g = 0; g < 4; ++g) {
            int a = sw(jj * 4 + g, b);
            p[g] = gbuf[a] + gbuf[4096 + a] + gbuf[8192 + a] + gbuf[12288 + a] + bias[g * HD + j];
          }
          if (L0) {
            const float* xr = strokes + ((size_t)b * TD + t) * 3;
            float x0 = xr[0], x1 = xr[1], x2 = xr[2];
#pragma unroll
            for (int g = 0; g < 4; ++g) {
              const float* wr = Wih0 + (size_t)(g * HD + j) * 3;
              p[g] += x0 * wr[0] + x1 * wr[1] + x2 * wr[2];
            }
          }
          float iv = sigmoidf_(p[0]);
          float fv = sigmoidf_(p[1]);
          float gv = tanhf(p[2]);
          float ov = sigmoidf_(p[3]);
          int ci = j * BD + b;       // CU-private, normal cached RMW
          float cn = fv * c[ci] + iv * gv;
          c[ci] = cn;
          hv[u2] = (unsigned)f2bf(ov * tanhf(cn));
        }
        unsigned packed = hv[0] | (hv[1] << 16);
        __hip_atomic_store((unsigned*)(hout + (size_t)b * HD + wgl * 16 + jp * 2), packed,
                           __ATOMIC_RELAXED, __HIP_MEMORY_SCOPE_AGENT);
      }
    }
    gridbar(cnt, (s + 1) * NBLK);
  }
}

// ---------------- output projection driver (2 WGs x 64 o-columns) ----------------
__device__ __forceinline__ void run_out(
    int wgo, int tid,
    const unsigned short* __restrict__ h2base,
    const unsigned short* __restrict__ Wo,   // bf16 [128][1024] padded
    const float* __restrict__ bo,
    float* __restrict__ outp, float* gbuf, int* cnt) {
  const int lane = tid & 63;
  const int w = tid >> 6;
  const int nl = lane & 15;
  const int kq8 = (lane >> 4) << 3;
  const int k0beg = w * 256;

  short8 bw[8][4];
#pragma unroll
  for (int ns = 0; ns < 4; ++ns) {
    int o = wgo * 64 + ns * 16 + nl;
    const unsigned short* wr = Wo + (size_t)o * HD + kq8 + k0beg;
#pragma unroll
    for (int k = 0; k < 8; ++k) bw[k][ns] = *(const short8*)(wr + k * 32);
  }

  const int bb = (lane >> 4) << 2;
  float* gs = gbuf + w * 4096;

  for (int s = 0; s < TD + 3; ++s) {
    int t = s - 3;
    if (t >= 0 && t < TD) {
      const unsigned short* arow = h2base + (size_t)(t & 1) * BH + nl * HD + kq8 + k0beg;

      f32x4 acc[4][4];
      const f32x4 z4 = {0.f, 0.f, 0.f, 0.f};
#pragma unroll
      for (int ns = 0; ns < 4; ++ns)
#pragma unroll
        for (int mt = 0; mt < 4; ++mt) acc[ns][mt] = z4;

      gemm_bw<8>(arow, bw, acc);

#pragma unroll
      for (int ns = 0; ns < 4; ++ns) {
        int gn = ns * 16 + nl;
#pragma unroll
        for (int mt = 0; mt < 4; ++mt)
#pragma unroll
          for (int r = 0; r < 4; ++r)
            gs[sw(gn, mt * 16 + bb + r)] = acc[ns][mt][r];
      }
      __syncthreads();

#pragma unroll
      for (int it = 0; it < 16; ++it) {
        int item = it * 256 + tid;
        int ol = item >> 6;
        int b = item & 63;
        int o = wgo * 64 + ol;
        int a = sw(ol, b);
        float v = gbuf[a] + gbuf[4096 + a] + gbuf[8192 + a] + gbuf[12288 + a] + bo[o];
        if (o < 121) outp[((size_t)b * TD + t) * 121 + o] = v;
      }
    }
    gridbar(cnt, (s + 1) * NBLK);
  }
}

// ---------------- main kernel ----------------
// WGs 0..63 layer0, 64..127 layer1, 128..191 layer2, 192..193 out-proj.
// Plain launch; 194 blocks <= 256 CUs, 1 block/CU co-resident (barrier-safe).
__global__ void __launch_bounds__(256, 1)
lstm_main(const float* __restrict__ strokes, const float* __restrict__ Wih0,
          float* __restrict__ outp, void* __restrict__ wsv) {
  __shared__ float gbuf[16384];  // 64 KB: 4 K-slices x [64 gn][64 b]
  unsigned short* u = (unsigned short*)wsv;
  float* fr = (float*)((char*)wsv + FBYTE_BASE);
  int* cnt = (int*)(fr + FOFF_CNT);

  const int wg = blockIdx.x;
  const int tid = threadIdx.x;

  if (wg < 64) {
    run_layer<true>(wg, tid, 0, nullptr, u + OFF_H0, fr + FOFF_C0,
                    nullptr, u + OFF_WHH0, fr + FOFF_B0, strokes, Wih0, gbuf, cnt);
  } else if (wg < 128) {
    run_layer<false>(wg - 64, tid, 1, u + OFF_H0, u + OFF_H1, fr + FOFF_C1,
                     u + OFF_WIH1, u + OFF_WHH1, fr + FOFF_B1, nullptr, nullptr, gbuf, cnt);
  } else if (wg < 192) {
    run_layer<false>(wg - 128, tid, 2, u + OFF_H1, u + OFF_H2, fr + FOFF_C2,
                     u + OFF_WIH2, u + OFF_WHH2, fr + FOFF_B2, nullptr, nullptr, gbuf, cnt);
  } else {
    run_out(wg - 192, tid, u + OFF_H2, u + OFF_WOUT, fr + FOFF_BOUT, outp, gbuf, cnt);
  }
}

extern "C" void kernel_launch(void* const* d_in, const int* in_sizes, int n_in,
                              void* d_out, int out_size, void* d_ws, size_t ws_size,
                              hipStream_t stream) {
  const float* strokes = (const float*)d_in[0];
  const float* Wih0 = (const float*)d_in[1];
  const float* Whh0 = (const float*)d_in[2];
  const float* bih0 = (const float*)d_in[3];
  const float* bhh0 = (const float*)d_in[4];
  const float* Wih1 = (const float*)d_in[5];
  const float* Whh1 = (const float*)d_in[6];
  const float* bih1 = (const float*)d_in[7];
  const float* bhh1 = (const float*)d_in[8];
  const float* Wih2 = (const float*)d_in[9];
  const float* Whh2 = (const float*)d_in[10];
  const float* bih2 = (const float*)d_in[11];
  const float* bhh2 = (const float*)d_in[12];
  const float* Wout = (const float*)d_in[13];
  const float* bout = (const float*)d_in[14];
  float* outp = (float*)d_out;

  hipLaunchKernelGGL(prep_kernel, dim3(4096), dim3(256), 0, stream,
                     Whh0, Wih1, Whh1, Wih2, Whh2, Wout,
                     bih0, bhh0, bih1, bhh1, bih2, bhh2, bout, d_ws);

  hipLaunchKernelGGL(lstm_main, dim3(NBLK), dim3(256), 0, stream,
                     strokes, Wih0, outp, d_ws);
}

// Round 6
// 9648.300 us; speedup vs baseline: 3.4127x; 1.2954x over previous
//
#include <hip/hip_runtime.h>

typedef __attribute__((ext_vector_type(8))) short short8;
typedef __attribute__((ext_vector_type(4))) float f32x4;
typedef __attribute__((ext_vector_type(4))) int int4v;

#define HD 1024
#define BD 64
#define TD 512
#define BH 65536UL  // 64*1024
#define NBLK 194

// ---------------- workspace layout ----------------
#define M4 4194304UL
#define OFF_WHH0 0UL
#define OFF_WIH1 (1UL * M4)
#define OFF_WHH1 (2UL * M4)
#define OFF_WIH2 (3UL * M4)
#define OFF_WHH2 (4UL * M4)
#define OFF_WOUT (5UL * M4)                 // 128 x 1024 (padded rows zeroed)
#define OFF_H0   (OFF_WOUT + 131072UL)      // [2][64][1024] each
#define OFF_H1   (OFF_H0 + 131072UL)
#define OFF_H2   (OFF_H1 + 131072UL)
#define USHORT_TOTAL (OFF_H2 + 131072UL)
#define FBYTE_BASE (USHORT_TOTAL * 2UL)
#define FOFF_C0 0UL                          // c stored [j][b] (transposed)
#define FOFF_C1 65536UL
#define FOFF_C2 131072UL
#define FOFF_B0 196608UL                     // combined biases b_ih+b_hh [4096]
#define FOFF_B1 200704UL
#define FOFF_B2 204800UL
#define FOFF_BOUT 208896UL                   // [128], pad zeroed
#define FOFF_CNT 209024UL                    // software grid-barrier counter
#define PREP_TOTAL 21704896UL

__device__ __forceinline__ unsigned short f2bf(float f) {
  union { float f; unsigned u; } v; v.f = f;
  unsigned r = v.u + 0x7fffu + ((v.u >> 16) & 1u);  // RNE
  return (unsigned short)(r >> 16);
}
__device__ __forceinline__ float sigmoidf_(float x) {
  return 1.0f / (1.0f + __expf(-x));
}
// LDS bank swizzle: inject gn's high bits into bank bits 0-1 and gn&7 into
// bits 2-4. Writes: ~4-way (was 8-way). Reads (fixed gn, consecutive b):
// b^const is a permutation -> 2-way (free).
__device__ __forceinline__ int sw(int gn, int b) {
  return gn * 64 + (b ^ (((gn & 7) << 2) | ((gn >> 3) & 3)));
}

// Raw agent-coherent (L2-bypass) 16B load. Volatile asm => program-order
// issue among themselves; vmcnt managed explicitly by AWAIT_N. sc1 = agent
// scope (same coherence path as R3/R4's verified intrinsic bypass loads).
__device__ __forceinline__ void gload16(int4v& dst, const unsigned short* p) {
  asm volatile("global_load_dwordx4 %0, %1, off sc1" : "=v"(dst) : "v"(p));
}
// Wait until <=N vmem ops outstanding, tying the consumed group's registers
// so dependent MFMAs schedule after. vmcnt is an in-order FIFO (m135):
// compiler-injected vmem between our loads only makes fixed-N waits
// stricter, never unsafe.
#define AWAIT_N(N, a0, a1, a2, a3) \
  asm volatile("s_waitcnt vmcnt(" #N ")" : "+v"(a0), "+v"(a1), "+v"(a2), "+v"(a3))

// Fence-free software grid barrier (monotonic counter; 515*194 < 2^31).
__device__ __forceinline__ void gridbar(int* cnt, int target) {
  asm volatile("s_waitcnt vmcnt(0)" ::: "memory");  // h stores retired at MALL
  __syncthreads();
  if (threadIdx.x == 0) {
    __hip_atomic_fetch_add(cnt, 1, __ATOMIC_RELAXED, __HIP_MEMORY_SCOPE_AGENT);
    while (__hip_atomic_load(cnt, __ATOMIC_RELAXED, __HIP_MEMORY_SCOPE_AGENT) < target)
      __builtin_amdgcn_s_sleep(1);
  }
  __syncthreads();
}

// ---------------- prep ----------------
__global__ void prep_kernel(const float* __restrict__ Whh0, const float* __restrict__ Wih1,
                            const float* __restrict__ Whh1, const float* __restrict__ Wih2,
                            const float* __restrict__ Whh2, const float* __restrict__ Wout,
                            const float* __restrict__ bih0, const float* __restrict__ bhh0,
                            const float* __restrict__ bih1, const float* __restrict__ bhh1,
                            const float* __restrict__ bih2, const float* __restrict__ bhh2,
                            const float* __restrict__ bout, void* wsv) {
  unsigned short* u = (unsigned short*)wsv;
  float* fr = (float*)((char*)wsv + FBYTE_BASE);
  size_t stride = (size_t)gridDim.x * blockDim.x;
  for (size_t i = (size_t)blockIdx.x * blockDim.x + threadIdx.x; i < PREP_TOTAL; i += stride) {
    if (i < 20971520UL) {
      size_t which = i >> 22;
      size_t off = i & (M4 - 1UL);
      const float* src = (which == 0) ? Whh0 : (which == 1) ? Wih1 :
                         (which == 2) ? Whh1 : (which == 3) ? Wih2 : Whh2;
      u[i] = f2bf(src[off]);
    } else if (i < 21102592UL) {
      size_t k = i - 20971520UL;
      size_t o = k >> 10, kk = k & 1023UL;
      u[i] = (o < 121) ? f2bf(Wout[o * 1024UL + kk]) : (unsigned short)0;
    } else if (i < 21495808UL) {
      u[i] = 0;
    } else if (i < 21692416UL) {
      fr[i - 21495808UL] = 0.0f;
    } else if (i < 21704704UL) {
      size_t k = i - 21692416UL;
      size_t l = k >> 12, n = k & 4095UL;
      const float* bi = (l == 0) ? bih0 : (l == 1) ? bih1 : bih2;
      const float* bh = (l == 0) ? bhh0 : (l == 1) ? bhh1 : bhh2;
      fr[FOFF_B0 + l * 4096UL + n] = bi[n] + bh[n];
    } else {
      size_t k = i - 21704704UL;
      fr[FOFF_BOUT + k] = (k < 121) ? bout[k] : 0.0f;
    }
  }
}

// ---------------- GEMM slice: register B, 6-deep explicit-vmcnt pipelined A ----------------
// 24 loads in flight steady-state. No over-issue: prefetch only real groups;
// tapered drain (20,16,12,8,4,0) so the LAST await leaves vmcnt==0 and no
// pending register writes survive the function (R5's crash: in-flight junk
// loads wrote VGPRs the allocator had reused in the epilogue).
template <int NK>
__device__ __forceinline__ void gemm_bw(const unsigned short* __restrict__ arow,
                                        const short8 (&bw)[NK][4],
                                        f32x4 (&acc)[4][4]) {
  static_assert(NK >= 6, "pipeline depth");
  int4v ap[6][4];
#pragma unroll
  for (int g = 0; g < 6; ++g)
#pragma unroll
    for (int mt = 0; mt < 4; ++mt)
      gload16(ap[g][mt], arow + mt * 16 * HD + g * 32);
#pragma unroll
  for (int k = 0; k < NK; ++k) {
    const int s = k % 6;
    // W = 20 while still issuing (issued = 24+4k); then 4*(NK-1-k).
    if (k <= NK - 6)          { AWAIT_N(20, ap[s][0], ap[s][1], ap[s][2], ap[s][3]); }
    else if (NK - 1 - k == 4) { AWAIT_N(16, ap[s][0], ap[s][1], ap[s][2], ap[s][3]); }
    else if (NK - 1 - k == 3) { AWAIT_N(12, ap[s][0], ap[s][1], ap[s][2], ap[s][3]); }
    else if (NK - 1 - k == 2) { AWAIT_N(8,  ap[s][0], ap[s][1], ap[s][2], ap[s][3]); }
    else if (NK - 1 - k == 1) { AWAIT_N(4,  ap[s][0], ap[s][1], ap[s][2], ap[s][3]); }
    else                      { AWAIT_N(0,  ap[s][0], ap[s][1], ap[s][2], ap[s][3]); }
#pragma unroll
    for (int mt = 0; mt < 4; ++mt) {
      short8 a = *(short8*)&ap[s][mt];
#pragma unroll
      for (int ns = 0; ns < 4; ++ns)
        acc[ns][mt] = __builtin_amdgcn_mfma_f32_16x16x32_bf16(a, bw[k][ns], acc[ns][mt], 0, 0, 0);
    }
    if (k + 6 < NK) {
#pragma unroll
      for (int mt = 0; mt < 4; ++mt)
        gload16(ap[s][mt], arow + mt * 16 * HD + (k + 6) * 32);
    }
  }
}

// ---------------- persistent-weight layer driver ----------------
template <bool L0>
__device__ __forceinline__ void run_layer(
    int wgl, int tid, int delay,
    const unsigned short* __restrict__ hinbase,  // upstream h (both parities), null for L0
    unsigned short* __restrict__ hbase,          // own h (both parities)
    float* __restrict__ c,                       // [1024][64] fp32 transposed
    const unsigned short* __restrict__ Wih,      // null for L0
    const unsigned short* __restrict__ Whh,
    const float* __restrict__ bias,
    const float* __restrict__ strokes,           // L0 only
    const float* __restrict__ Wih0,              // L0 only, fp32 [4096][3]
    float* gbuf, int* cnt) {
  constexpr int NK = L0 ? 8 : 16;
  const int lane = tid & 63;
  const int w = tid >> 6;
  const int nl = lane & 15;
  const int kq8 = (lane >> 4) << 3;

  const unsigned short* Wm;
  int k0beg;
  bool useHin;
  if (L0) { Wm = Whh; k0beg = w * 256; useHin = false; }
  else    { Wm = (w < 2) ? Wih : Whh; k0beg = (w & 1) * 512; useHin = (w < 2); }

  short8 bw[NK][4];
#pragma unroll
  for (int ns = 0; ns < 4; ++ns) {
    int jgl = wgl * 16 + ns * 4 + (nl >> 2);
    int row = (nl & 3) * HD + jgl;                 // gate-major weight row
    const unsigned short* wr = Wm + (size_t)row * HD + kq8 + k0beg;
#pragma unroll
    for (int k = 0; k < NK; ++k) bw[k][ns] = *(const short8*)(wr + k * 32);
  }

  const int bb = (lane >> 4) << 2;
  float* gs = gbuf + w * 4096;

  for (int s = 0; s < TD + 3; ++s) {
    int t = s - delay;
    if (t >= 0 && t < TD) {
      const unsigned short* A = useHin ? (hinbase + (size_t)(t & 1) * BH)
                                       : (hbase + (size_t)((t - 1) & 1) * BH);
      const unsigned short* arow = A + nl * HD + kq8 + k0beg;

      f32x4 acc[4][4];
      const f32x4 z4 = {0.f, 0.f, 0.f, 0.f};
#pragma unroll
      for (int ns = 0; ns < 4; ++ns)
#pragma unroll
        for (int mt = 0; mt < 4; ++mt) acc[ns][mt] = z4;

      gemm_bw<NK>(arow, bw, acc);

#pragma unroll
      for (int ns = 0; ns < 4; ++ns) {
        int gn = ns * 16 + nl;
#pragma unroll
        for (int mt = 0; mt < 4; ++mt)
#pragma unroll
          for (int r = 0; r < 4; ++r)
            gs[sw(gn, mt * 16 + bb + r)] = acc[ns][mt][r];
      }
      __syncthreads();

      unsigned short* hout = hbase + (size_t)(t & 1) * BH;
#pragma unroll
      for (int it = 0; it < 2; ++it) {
        int item = it * 256 + tid;
        int jp = item >> 6;          // 0..7 pair of j
        int b = item & 63;
        unsigned hv[2];
#pragma unroll
        for (int u2 = 0; u2 < 2; ++u2) {
          int jj = jp * 2 + u2;
          int j = wgl * 16 + jj;
          float p[4];
#pragma unroll
          for (int g = 0; g < 4; ++g) {
            int a = sw(jj * 4 + g, b);
            p[g] = gbuf[a] + gbuf[4096 + a] + gbuf[8192 + a] + gbuf[12288 + a] + bias[g * HD + j];
          }
          if (L0) {
            const float* xr = strokes + ((size_t)b * TD + t) * 3;
            float x0 = xr[0], x1 = xr[1], x2 = xr[2];
#pragma unroll
            for (int g = 0; g < 4; ++g) {
              const float* wr = Wih0 + (size_t)(g * HD + j) * 3;
              p[g] += x0 * wr[0] + x1 * wr[1] + x2 * wr[2];
            }
          }
          float iv = sigmoidf_(p[0]);
          float fv = sigmoidf_(p[1]);
          float gv = tanhf(p[2]);
          float ov = sigmoidf_(p[3]);
          int ci = j * BD + b;       // CU-private, normal cached RMW
          float cn = fv * c[ci] + iv * gv;
          c[ci] = cn;
          hv[u2] = (unsigned)f2bf(ov * tanhf(cn));
        }
        unsigned packed = hv[0] | (hv[1] << 16);
        __hip_atomic_store((unsigned*)(hout + (size_t)b * HD + wgl * 16 + jp * 2), packed,
                           __ATOMIC_RELAXED, __HIP_MEMORY_SCOPE_AGENT);
      }
    }
    gridbar(cnt, (s + 1) * NBLK);
  }
}

// ---------------- output projection driver (2 WGs x 64 o-columns) ----------------
__device__ __forceinline__ void run_out(
    int wgo, int tid,
    const unsigned short* __restrict__ h2base,
    const unsigned short* __restrict__ Wo,   // bf16 [128][1024] padded
    const float* __restrict__ bo,
    float* __restrict__ outp, float* gbuf, int* cnt) {
  const int lane = tid & 63;
  const int w = tid >> 6;
  const int nl = lane & 15;
  const int kq8 = (lane >> 4) << 3;
  const int k0beg = w * 256;

  short8 bw[8][4];
#pragma unroll
  for (int ns = 0; ns < 4; ++ns) {
    int o = wgo * 64 + ns * 16 + nl;
    const unsigned short* wr = Wo + (size_t)o * HD + kq8 + k0beg;
#pragma unroll
    for (int k = 0; k < 8; ++k) bw[k][ns] = *(const short8*)(wr + k * 32);
  }

  const int bb = (lane >> 4) << 2;
  float* gs = gbuf + w * 4096;

  for (int s = 0; s < TD + 3; ++s) {
    int t = s - 3;
    if (t >= 0 && t < TD) {
      const unsigned short* arow = h2base + (size_t)(t & 1) * BH + nl * HD + kq8 + k0beg;

      f32x4 acc[4][4];
      const f32x4 z4 = {0.f, 0.f, 0.f, 0.f};
#pragma unroll
      for (int ns = 0; ns < 4; ++ns)
#pragma unroll
        for (int mt = 0; mt < 4; ++mt) acc[ns][mt] = z4;

      gemm_bw<8>(arow, bw, acc);

#pragma unroll
      for (int ns = 0; ns < 4; ++ns) {
        int gn = ns * 16 + nl;
#pragma unroll
        for (int mt = 0; mt < 4; ++mt)
#pragma unroll
          for (int r = 0; r < 4; ++r)
            gs[sw(gn, mt * 16 + bb + r)] = acc[ns][mt][r];
      }
      __syncthreads();

#pragma unroll
      for (int it = 0; it < 16; ++it) {
        int item = it * 256 + tid;
        int ol = item >> 6;
        int b = item & 63;
        int o = wgo * 64 + ol;
        int a = sw(ol, b);
        float v = gbuf[a] + gbuf[4096 + a] + gbuf[8192 + a] + gbuf[12288 + a] + bo[o];
        if (o < 121) outp[((size_t)b * TD + t) * 121 + o] = v;
      }
    }
    gridbar(cnt, (s + 1) * NBLK);
  }
}

// ---------------- main kernel ----------------
// WGs 0..63 layer0, 64..127 layer1, 128..191 layer2, 192..193 out-proj.
// Plain launch; 194 blocks <= 256 CUs, co-resident (barrier-safe).
__global__ void __launch_bounds__(256, 1)
lstm_main(const float* __restrict__ strokes, const float* __restrict__ Wih0,
          float* __restrict__ outp, void* __restrict__ wsv) {
  __shared__ float gbuf[16384];  // 64 KB: 4 K-slices x [64 gn][64 b]
  unsigned short* u = (unsigned short*)wsv;
  float* fr = (float*)((char*)wsv + FBYTE_BASE);
  int* cnt = (int*)(fr + FOFF_CNT);

  const int wg = blockIdx.x;
  const int tid = threadIdx.x;

  if (wg < 64) {
    run_layer<true>(wg, tid, 0, nullptr, u + OFF_H0, fr + FOFF_C0,
                    nullptr, u + OFF_WHH0, fr + FOFF_B0, strokes, Wih0, gbuf, cnt);
  } else if (wg < 128) {
    run_layer<false>(wg - 64, tid, 1, u + OFF_H0, u + OFF_H1, fr + FOFF_C1,
                     u + OFF_WIH1, u + OFF_WHH1, fr + FOFF_B1, nullptr, nullptr, gbuf, cnt);
  } else if (wg < 192) {
    run_layer<false>(wg - 128, tid, 2, u + OFF_H1, u + OFF_H2, fr + FOFF_C2,
                     u + OFF_WIH2, u + OFF_WHH2, fr + FOFF_B2, nullptr, nullptr, gbuf, cnt);
  } else {
    run_out(wg - 192, tid, u + OFF_H2, u + OFF_WOUT, fr + FOFF_BOUT, outp, gbuf, cnt);
  }
}

extern "C" void kernel_launch(void* const* d_in, const int* in_sizes, int n_in,
                              void* d_out, int out_size, void* d_ws, size_t ws_size,
                              hipStream_t stream) {
  const float* strokes = (const float*)d_in[0];
  const float* Wih0 = (const float*)d_in[1];
  const float* Whh0 = (const float*)d_in[2];
  const float* bih0 = (const float*)d_in[3];
  const float* bhh0 = (const float*)d_in[4];
  const float* Wih1 = (const float*)d_in[5];
  const float* Whh1 = (const float*)d_in[6];
  const float* bih1 = (const float*)d_in[7];
  const float* bhh1 = (const float*)d_in[8];
  const float* Wih2 = (const float*)d_in[9];
  const float* Whh2 = (const float*)d_in[10];
  const float* bih2 = (const float*)d_in[11];
  const float* bhh2 = (const float*)d_in[12];
  const float* Wout = (const float*)d_in[13];
  const float* bout = (const float*)d_in[14];
  float* outp = (float*)d_out;

  hipLaunchKernelGGL(prep_kernel, dim3(4096), dim3(256), 0, stream,
                     Whh0, Wih1, Whh1, Wih2, Whh2, Wout,
                     bih0, bhh0, bih1, bhh1, bih2, bhh2, bout, d_ws);

  hipLaunchKernelGGL(lstm_main, dim3(NBLK), dim3(256), 0, stream,
                     strokes, Wih0, outp, d_ws);
}